// Round 7
// baseline (740.367 us; speedup 1.0000x reference)
//
#include <hip/hip_runtime.h>
#include <stdint.h>

#define VN   1000000
#define VDIM 256
#define GDIM 256
#define NH   16
#define NG   50000
#define HIDD 128
#define NTILES 15625   // VN / 64

using bf16x8 = __attribute__((ext_vector_type(8))) __bf16;
using f32x4  = __attribute__((ext_vector_type(4))) float;
using u16x4  = __attribute__((ext_vector_type(4))) unsigned short;

__device__ __forceinline__ unsigned short f2bf(float f) {
  __bf16 h = (__bf16)f;                       // native RNE cvt (v_cvt_pk_bf16_f32)
  return __builtin_bit_cast(unsigned short, h);
}
__device__ __forceinline__ bf16x8 pack8(float4 a, float4 b) {
  bf16x8 r;
  r[0] = (__bf16)a.x; r[1] = (__bf16)a.y; r[2] = (__bf16)a.z; r[3] = (__bf16)a.w;
  r[4] = (__bf16)b.x; r[5] = (__bf16)b.y; r[6] = (__bf16)b.z; r[7] = (__bf16)b.w;
  return r;
}
__device__ __forceinline__ f32x4 fzero4() { f32x4 z = {0.f, 0.f, 0.f, 0.f}; return z; }

// ---------------- weight prep: fp32 -> bf16 in MFMA B-fragment order ----------------
// For W[K][N]: frag element idx = ((c*(K/32)+s)*64 + lane)*8 + j  holds W[32s+8*(lane>>4)+j][16c+(lane&15)]
__global__ void k_prep(const float* __restrict__ s1, const float* __restrict__ s2,
                       const float* __restrict__ t1, const float* __restrict__ t2,
                       unsigned short* __restrict__ WB) {
  int t = blockIdx.x * 256 + threadIdx.x;
  const float* W; unsigned short* dst; int K, N, lid;
  if (t < 32768)       { W = s1; dst = WB;          K = 256; N = 128; lid = t; }
  else if (t < 65536)  { W = t1; dst = WB + 32768;  K = 256; N = 128; lid = t - 32768; }
  else if (t < 98304)  { W = t2; dst = WB + 65536;  K = 128; N = 256; lid = t - 65536; }
  else if (t < 100352) { W = s2; dst = WB + 98304;  K = 128; N = 16;  lid = t - 98304; }
  else return;
  int j = lid & 7, l = (lid >> 3) & 63, rem = lid >> 9;
  int KS = K >> 5;
  int s = rem % KS, c = rem / KS;
  int row = 32 * s + 8 * (l >> 4) + j;
  int col = 16 * c + (l & 15);
  dst[lid] = f2bf(W[row * N + col]);
}

// ---------------- zero: out [NG*GDIM] + denom [NG*NH] ----------------
__global__ void k_zero(float* __restrict__ out, float* __restrict__ denom) {
  int i = blockIdx.x * 256 + threadIdx.x;
  float4 z = make_float4(0.f, 0.f, 0.f, 0.f);
  if (i < NG * GDIM / 4) ((float4*)out)[i] = z;
  int j = i - NG * GDIM / 4;
  if (j >= 0 && j < NG * NH / 4) ((float4*)denom)[j] = z;
}

// ---------------- fused main: one 64-row tile per block, A-frags direct from global ----------------
// LDS (36 KB): Hs [0,16384); Ts [16384,32768); exs f32[64][16] [32768,36864)
// No X staging: layer-1 A-fragments are built straight from global fp32 (2x float4 + cvt_pk),
// 64 independent loads per wave pipelined inside the MFMA loop. 2 barriers total.
__global__ __launch_bounds__(256, 4) void k_main(
    const float* __restrict__ X,
    const unsigned short* __restrict__ WBs1,
    const unsigned short* __restrict__ WBt1,
    const unsigned short* __restrict__ WBs2,
    const unsigned short* __restrict__ WBt2,
    const int* __restrict__ seg,
    float* __restrict__ denom,
    float* __restrict__ out) {
  __shared__ __align__(16) char U[36864];
  char* const Hs = U;
  char* const Ts = U + 16384;
  float* const exs = (float*)(U + 32768);

  const int tid  = threadIdx.x;
  const int lane = tid & 63;
  const int w    = tid >> 6;
  const int lg   = lane >> 4;
  const size_t base = (size_t)blockIdx.x * 64;

  // per-lane graph id for the tile's 64 rows (lane <-> row)
  const int gv = seg[base + lane];
  const int gp = __shfl_up(gv, 1, 64);
  const unsigned long long bmask = __ballot(gv != gp) | 1ull;  // segment-start rows

  // ---- Phase B: C1[64][256] = relu(X @ [Sw1|Tw1]); waves 0,1 -> Sw1, 2,3 -> Tw1
  {
    const unsigned short* WB = (w < 2) ? WBs1 : WBt1;
    const int cbase = (w & 1) * 4;
    const int m = lane & 15;
    // per-r row base pointers; A-frag cols for ks: 32*ks + 8*lg + j, j=0..7
    const float* xp0 = X + (base + m)      * VDIM + 8 * lg;
    const float* xp1 = xp0 + 16 * VDIM;
    const float* xp2 = xp1 + 16 * VDIM;
    const float* xp3 = xp2 + 16 * VDIM;

    f32x4 acc[4][4];
    #pragma unroll
    for (int r = 0; r < 4; ++r)
      #pragma unroll
      for (int c = 0; c < 4; ++c) acc[r][c] = fzero4();

    #pragma unroll
    for (int ks = 0; ks < 8; ++ks) {
      bf16x8 A[4];
      {
        const float4* p0 = (const float4*)(xp0 + 32 * ks);
        const float4* p1 = (const float4*)(xp1 + 32 * ks);
        const float4* p2 = (const float4*)(xp2 + 32 * ks);
        const float4* p3 = (const float4*)(xp3 + 32 * ks);
        A[0] = pack8(p0[0], p0[1]);
        A[1] = pack8(p1[0], p1[1]);
        A[2] = pack8(p2[0], p2[1]);
        A[3] = pack8(p3[0], p3[1]);
      }
      #pragma unroll
      for (int ci = 0; ci < 4; ++ci) {
        bf16x8 B = *(const bf16x8*)(WB + (size_t)(((cbase + ci) * 8 + ks) * 64 + lane) * 8);
        #pragma unroll
        for (int r = 0; r < 4; ++r)
          acc[r][ci] = __builtin_amdgcn_mfma_f32_16x16x32_bf16(A[r], B, acc[r][ci], 0, 0, 0);
      }
    }

    // relu + bf16 -> Hs (waves 0,1) / Ts (waves 2,3), [64][128] 256B rows, swizzled
    char* const dst = (w < 2) ? Hs : Ts;
    #pragma unroll
    for (int ci = 0; ci < 4; ++ci) {
      int colf = cbase + ci;
      #pragma unroll
      for (int r = 0; r < 4; ++r) {
        #pragma unroll
        for (int j = 0; j < 4; ++j) {
          int row = 16 * r + 4 * lg + j;
          int col = 16 * colf + m;
          float v = acc[r][ci][j];
          v = v > 0.f ? v : 0.f;
          *(unsigned short*)(dst + row * 256 + ((col * 2) ^ ((row & 7) << 4))) = f2bf(v);
        }
      }
    }
  }
  __syncthreads();   // bar1: Hs/Ts complete

  // ---- Phase C1: scores = H1 @ Sw2 (wave w -> rows 16w..16w+15); ex -> exs + denom atomics
  {
    f32x4 sa = fzero4();
    #pragma unroll
    for (int ks = 0; ks < 4; ++ks) {
      int row = 16 * w + (lane & 15);
      int cb = 64 * ks + 16 * lg;
      bf16x8 A2 = *(const bf16x8*)(Hs + row * 256 + (cb ^ ((row & 7) << 4)));
      bf16x8 B2 = *(const bf16x8*)(WBs2 + (size_t)(ks * 64 + lane) * 8);
      sa = __builtin_amdgcn_mfma_f32_16x16x32_bf16(A2, B2, sa, 0, 0, 0);
    }
    const int h = lane & 15;
    const int rowbase = 16 * w + 4 * lg;
    float ex[4]; int gs[4];
    #pragma unroll
    for (int j = 0; j < 4; ++j) {
      ex[j] = __expf(sa[j]);                       // |score| ~< 1.5: no max-subtract needed
      gs[j] = __shfl(gv, rowbase + j, 64);
      exs[(rowbase + j) * 16 + h] = ex[j];
    }
    float accd = ex[0]; int gcur = gs[0];
    #pragma unroll
    for (int j = 1; j < 4; ++j) {
      if (gs[j] == gcur) accd += ex[j];
      else { atomicAdd(denom + (size_t)gcur * NH + h, accd); gcur = gs[j]; accd = ex[j]; }
    }
    atomicAdd(denom + (size_t)gcur * NH + h, accd);
  }

  // ---- Phase C2: R = T1 @ Tw2 ; wave w -> col-frags 4w..4w+3
  f32x4 racc[4][4];
  #pragma unroll
  for (int r = 0; r < 4; ++r)
    #pragma unroll
    for (int c = 0; c < 4; ++c) racc[r][c] = fzero4();
  #pragma unroll
  for (int ks = 0; ks < 4; ++ks) {
    bf16x8 A[4];
    #pragma unroll
    for (int r = 0; r < 4; ++r) {
      int row = 16 * r + (lane & 15);
      int cbyte = 64 * ks + 16 * lg;
      A[r] = *(const bf16x8*)(Ts + row * 256 + (cbyte ^ ((row & 7) << 4)));
    }
    #pragma unroll
    for (int ci = 0; ci < 4; ++ci) {
      bf16x8 B = *(const bf16x8*)(WBt2 + (size_t)(((4 * w + ci) * 4 + ks) * 64 + lane) * 8);
      #pragma unroll
      for (int r = 0; r < 4; ++r)
        racc[r][ci] = __builtin_amdgcn_mfma_f32_16x16x32_bf16(A[r], B, racc[r][ci], 0, 0, 0);
    }
  }
  __syncthreads();   // bar2: exs fully written by all waves

  // ---- Phase D: racc = relu(racc) * ex[row][head]  (heads 4w..4w+3)
  #pragma unroll
  for (int r = 0; r < 4; ++r)
    #pragma unroll
    for (int j = 0; j < 4; ++j) {
      int row = 16 * r + 4 * lg + j;
      f32x4 wr = *(const f32x4*)(exs + row * 16 + 4 * w);
      #pragma unroll
      for (int ci = 0; ci < 4; ++ci) {
        float v = racc[r][ci][j];
        v = v > 0.f ? v : 0.f;
        racc[r][ci][j] = v * wr[ci];
      }
    }

  // ---- Phase E: in-register segmented column sums; interior -> store, edge -> atomic
  unsigned long long m = bmask;
  while (m) {
    int a = __builtin_ctzll(m);
    m &= m - 1;
    int b = m ? __builtin_ctzll(m) : 64;
    int g = __shfl(gv, a, 64);
    f32x4 s = fzero4();
    #pragma unroll
    for (int r = 0; r < 4; ++r)
      #pragma unroll
      for (int j = 0; j < 4; ++j) {
        int row = 16 * r + 4 * lg + j;
        float msk = ((unsigned)(row - a) < (unsigned)(b - a)) ? 1.f : 0.f;
        #pragma unroll
        for (int ci = 0; ci < 4; ++ci) s[ci] = fmaf(msk, racc[r][ci][j], s[ci]);
      }
    #pragma unroll
    for (int ci = 0; ci < 4; ++ci) {
      s[ci] += __shfl_xor(s[ci], 16, 64);
      s[ci] += __shfl_xor(s[ci], 32, 64);
    }
    bool edge = (a == 0) || (b == 64);
    if (lane < 16) {
      float* dst = out + (size_t)g * GDIM + 64 * w + lane;
      if (edge) {
        atomicAdd(dst,      s[0]); atomicAdd(dst + 16, s[1]);
        atomicAdd(dst + 32, s[2]); atomicAdd(dst + 48, s[3]);
      } else {
        dst[0] = s[0]; dst[16] = s[1]; dst[32] = s[2]; dst[48] = s[3];
      }
    }
  }
}

// ---------------- epilogue: out[g][c] /= denom[g][c/16]; empty graphs -> 0 ----------------
__global__ void k_div(float* __restrict__ out, const float* __restrict__ denom) {
  int i = blockIdx.x * 256 + threadIdx.x;     // one float4 of out per thread
  if (i >= NG * GDIM / 4) return;
  float d = denom[(size_t)(i >> 6) * NH + ((i & 63) >> 2)];
  float r = d > 0.f ? 1.0f / d : 0.f;
  float4 v = ((float4*)out)[i];
  v.x *= r; v.y *= r; v.z *= r; v.w *= r;
  ((float4*)out)[i] = v;
}

extern "C" void kernel_launch(void* const* d_in, const int* in_sizes, int n_in,
                              void* d_out, int out_size, void* d_ws, size_t ws_size,
                              hipStream_t stream) {
  (void)in_sizes; (void)n_in; (void)out_size; (void)ws_size;
  const float* X  = (const float*)d_in[0];
  const int* seg  = (const int*)d_in[1];
  const float* s1 = (const float*)d_in[3];
  const float* s2 = (const float*)d_in[4];
  const float* t1 = (const float*)d_in[5];
  const float* t2 = (const float*)d_in[6];
  float* out = (float*)d_out;
  char* ws = (char*)d_ws;

  // ws layout: [0, 401408) weight frags bf16; [1<<19, +3.2MB) denom f32[NG][NH]
  unsigned short* WB = (unsigned short*)ws;
  float* denom = (float*)(ws + (1 << 19));

  k_prep<<<392, 256, 0, stream>>>(s1, s2, t1, t2, WB);
  k_zero<<<13282, 256, 0, stream>>>(out, denom);
  k_main<<<NTILES, 256, 0, stream>>>(X, WB, WB + 32768, WB + 98304, WB + 65536,
                                     seg, denom, out);
  k_div<<<12500, 256, 0, stream>>>(out, denom);
}

// Round 8
// 661.249 us; speedup vs baseline: 1.1197x; 1.1197x over previous
//
#include <hip/hip_runtime.h>
#include <stdint.h>

#define VN   1000000
#define VDIM 256
#define GDIM 256
#define NH   16
#define NG   50000
#define HIDD 128
#define NTILES 15625   // VN / 64
#define TPB   5        // tiles per block; 15625 = 5 * 3125

using bf16x8 = __attribute__((ext_vector_type(8))) __bf16;
using f32x4  = __attribute__((ext_vector_type(4))) float;
using u16x4  = __attribute__((ext_vector_type(4))) unsigned short;

__device__ __forceinline__ unsigned short f2bf(float f) {
  __bf16 h = (__bf16)f;
  return __builtin_bit_cast(unsigned short, h);
}
__device__ __forceinline__ bf16x8 pack8(f32x4 a, f32x4 b) {
  bf16x8 r;
  r[0] = (__bf16)a[0]; r[1] = (__bf16)a[1]; r[2] = (__bf16)a[2]; r[3] = (__bf16)a[3];
  r[4] = (__bf16)b[0]; r[5] = (__bf16)b[1]; r[6] = (__bf16)b[2]; r[7] = (__bf16)b[3];
  return r;
}
__device__ __forceinline__ f32x4 fzero4() { f32x4 z = {0.f, 0.f, 0.f, 0.f}; return z; }

// async global->LDS, 16B/lane; LDS dest = wave-uniform base + lane*16
typedef __attribute__((address_space(1))) const void* gas_t;
typedef __attribute__((address_space(3))) void* las_t;
__device__ __forceinline__ void gld16(const void* g, void* l) {
  __builtin_amdgcn_global_load_lds((gas_t)g, (las_t)l, 16, 0, 0);
}

// ---------------- weight prep: fp32 -> bf16 in MFMA B-fragment order ----------------
__global__ void k_prep(const float* __restrict__ s1, const float* __restrict__ s2,
                       const float* __restrict__ t1, const float* __restrict__ t2,
                       unsigned short* __restrict__ WB) {
  int t = blockIdx.x * 256 + threadIdx.x;
  const float* W; unsigned short* dst; int K, N, lid;
  if (t < 32768)       { W = s1; dst = WB;          K = 256; N = 128; lid = t; }
  else if (t < 65536)  { W = t1; dst = WB + 32768;  K = 256; N = 128; lid = t - 32768; }
  else if (t < 98304)  { W = t2; dst = WB + 65536;  K = 128; N = 256; lid = t - 65536; }
  else if (t < 100352) { W = s2; dst = WB + 98304;  K = 128; N = 16;  lid = t - 98304; }
  else return;
  int j = lid & 7, l = (lid >> 3) & 63, rem = lid >> 9;
  int KS = K >> 5;
  int s = rem % KS, c = rem / KS;
  int row = 32 * s + 8 * (l >> 4) + j;
  int col = 16 * c + (l & 15);
  dst[lid] = f2bf(W[row * N + col]);
}

// ---------------- zero: out [NG*GDIM] + denom [NG*NH] ----------------
__global__ void k_zero(float* __restrict__ out, float* __restrict__ denom) {
  int i = blockIdx.x * 256 + threadIdx.x;
  float4 z = make_float4(0.f, 0.f, 0.f, 0.f);
  if (i < NG * GDIM / 4) ((float4*)out)[i] = z;
  int j = i - NG * GDIM / 4;
  if (j >= 0 && j < NG * NH / 4) ((float4*)denom)[j] = z;
}

// ---------------- fused main: 512 thr, 1 block/CU, glds-pipelined fp32 X ----------------
// LDS (100 KB): Xs f32[64][256] swizzled [0,65536); Hs [65536,81920); Ts [81920,98304);
//               exs f32[64][16] [98304,102400)
// Per tile: [vmcnt(0)+bar] B(read Xs, MFMA, write Hs/Ts) [bar] stage(t+1: 8 glds/wave)
//           C1 C2 [lgkm+raw bar] D E.  Weights live in registers: no in-loop VMEM consume
//           -> in-order vmcnt never force-drains the glds prefetch.
__global__ __launch_bounds__(512)
__attribute__((amdgpu_waves_per_eu(2, 2)))
void k_main(
    const float* __restrict__ X,
    const unsigned short* __restrict__ WBs1,
    const unsigned short* __restrict__ WBt1,
    const unsigned short* __restrict__ WBs2,
    const unsigned short* __restrict__ WBt2,
    const int* __restrict__ seg,
    float* __restrict__ denom,
    float* __restrict__ out) {
  __shared__ __align__(16) char U[102400];
  float* const Xs = (float*)U;
  char*  const Hs = U + 65536;
  char*  const Ts = U + 81920;
  float* const exs = (float*)(U + 98304);

  const int tid  = threadIdx.x;
  const int lane = tid & 63;
  const int w    = tid >> 6;       // 0..7
  const int lg   = lane >> 4;
  const int ml   = lane & 15;
  const int t0   = blockIdx.x * TPB;

  // ---- hoist ALL weight B-fragments to registers (loop-invariant, ~112 VGPR)
  bf16x8 W1[2][8];                 // layer1: waves 0-3 Sw1 cf {2w,2w+1}; waves 4-7 Tw1
  {
    const unsigned short* Wb = (w < 4) ? WBs1 : WBt1;
    const int cw = 2 * (w & 3);
    #pragma unroll
    for (int ci = 0; ci < 2; ++ci)
      #pragma unroll
      for (int ks = 0; ks < 8; ++ks)
        W1[ci][ks] = *(const bf16x8*)(Wb + (size_t)(((cw + ci) * 8 + ks) * 64 + lane) * 8);
  }
  bf16x8 W2[2][4];                 // Tw2 cf {2w,2w+1} of 16
  #pragma unroll
  for (int ci = 0; ci < 2; ++ci)
    #pragma unroll
    for (int ks = 0; ks < 4; ++ks)
      W2[ci][ks] = *(const bf16x8*)(WBt2 + (size_t)(((2 * w + ci) * 4 + ks) * 64 + lane) * 8);
  bf16x8 WS2[4];                   // Sw2 (16 cols)
  #pragma unroll
  for (int ks = 0; ks < 4; ++ks)
    WS2[ks] = *(const bf16x8*)(WBs2 + (size_t)(ks * 64 + lane) * 8);

  // ---- preload seg ids for all TPB tiles (no in-loop global loads)
  int gvs[TPB];
  #pragma unroll
  for (int i = 0; i < TPB; ++i) gvs[i] = seg[(size_t)(t0 + i) * 64 + lane];

  // ---- glds stage: 64KB fp32 tile, linear LDS dest, inverse-swizzled global source
  auto stage = [&](int t) {
    const char* gX = (const char*)X + (size_t)t * 64 * 1024;
    #pragma unroll
    for (int i = 0; i < 8; ++i) {
      const int cb = i * 512 + w * 64;            // wave-uniform chunk base
      const int chunk = cb + lane;
      const int row = chunk >> 6, c16 = chunk & 63;
      const char* src = gX + row * 1024 + ((c16 * 16) ^ ((row & 7) << 4));
      gld16(src, (char*)Xs + cb * 16);
    }
  };

  stage(t0);   // prologue

  #pragma unroll
  for (int it = 0; it < TPB; ++it) {
    asm volatile("s_waitcnt vmcnt(0)" ::: "memory");   // Xs(t) landed (also retires E(t-1) stores)
    __builtin_amdgcn_s_barrier();
    __builtin_amdgcn_sched_barrier(0);

    const int gv = gvs[it];
    const int gp = __shfl_up(gv, 1, 64);
    const unsigned long long bmask = __ballot(gv != gp) | 1ull;

    // ---- Phase B: C1[64][256] = relu(X @ [Sw1|Tw1]); fp32 LDS reads + cvt_pk -> A-frags
    f32x4 acc[4][2];
    #pragma unroll
    for (int r = 0; r < 4; ++r) { acc[r][0] = fzero4(); acc[r][1] = fzero4(); }
    #pragma unroll
    for (int ks = 0; ks < 8; ++ks) {
      bf16x8 A[4];
      #pragma unroll
      for (int r = 0; r < 4; ++r) {
        const int row = 16 * r + ml;
        const int sw = (row & 7) << 4;
        const int cbyte = 128 * ks + 32 * lg;
        const char* p = (const char*)Xs + row * 1024;
        f32x4 lo = *(const f32x4*)(p + (cbyte ^ sw));
        f32x4 hi = *(const f32x4*)(p + ((cbyte + 16) ^ sw));
        A[r] = pack8(lo, hi);
      }
      #pragma unroll
      for (int ci = 0; ci < 2; ++ci)
        #pragma unroll
        for (int r = 0; r < 4; ++r)
          acc[r][ci] = __builtin_amdgcn_mfma_f32_16x16x32_bf16(A[r], W1[ci][ks], acc[r][ci], 0, 0, 0);
    }
    // relu + bf16 -> Hs (waves 0-3) / Ts (waves 4-7), swizzled 256B rows
    {
      char* const dst = (w < 4) ? Hs : Ts;
      const int cw = 2 * (w & 3);
      #pragma unroll
      for (int ci = 0; ci < 2; ++ci) {
        const int colf = cw + ci;
        #pragma unroll
        for (int r = 0; r < 4; ++r)
          #pragma unroll
          for (int j = 0; j < 4; ++j) {
            const int row = 16 * r + 4 * lg + j;
            const int col = 16 * colf + ml;
            float v = acc[r][ci][j];
            v = v > 0.f ? v : 0.f;
            *(unsigned short*)(dst + row * 256 + ((col * 2) ^ ((row & 7) << 4))) = f2bf(v);
          }
      }
    }
    __syncthreads();   // Xs reads done + Hs/Ts visible (no glds outstanding here)

    if (it + 1 < TPB) stage(t0 + it + 1);   // prefetch streams under C1/C2/D/E

    // ---- Phase C1 (waves 0-3): scores rows 16w..16w+15 -> ex -> exs + denom atomics
    if (w < 4) {
      f32x4 sa = fzero4();
      #pragma unroll
      for (int ks = 0; ks < 4; ++ks) {
        const int row = 16 * w + ml;
        const int cb = 64 * ks + 16 * lg;
        bf16x8 A2 = *(const bf16x8*)(Hs + row * 256 + (cb ^ ((row & 7) << 4)));
        sa = __builtin_amdgcn_mfma_f32_16x16x32_bf16(A2, WS2[ks], sa, 0, 0, 0);
      }
      const int rowbase = 16 * w + 4 * lg;
      float ex[4]; int gs[4];
      #pragma unroll
      for (int j = 0; j < 4; ++j) {
        ex[j] = __expf(sa[j]);                     // |score| ~< 1.5: no max-subtract needed
        gs[j] = __shfl(gv, rowbase + j, 64);
        exs[(rowbase + j) * 16 + ml] = ex[j];
      }
      float accd = ex[0]; int gcur = gs[0];
      #pragma unroll
      for (int j = 1; j < 4; ++j) {
        if (gs[j] == gcur) accd += ex[j];
        else { atomicAdd(denom + (size_t)gcur * NH + ml, accd); gcur = gs[j]; accd = ex[j]; }
      }
      atomicAdd(denom + (size_t)gcur * NH + ml, accd);
    }

    // ---- Phase C2: R = T1 @ Tw2; wave w -> col-frags {2w, 2w+1}
    f32x4 racc[4][2];
    #pragma unroll
    for (int r = 0; r < 4; ++r) { racc[r][0] = fzero4(); racc[r][1] = fzero4(); }
    #pragma unroll
    for (int ks = 0; ks < 4; ++ks) {
      bf16x8 A[4];
      #pragma unroll
      for (int r = 0; r < 4; ++r) {
        const int row = 16 * r + ml;
        const int cbyte = 64 * ks + 16 * lg;
        A[r] = *(const bf16x8*)(Ts + row * 256 + (cbyte ^ ((row & 7) << 4)));
      }
      #pragma unroll
      for (int ci = 0; ci < 2; ++ci)
        #pragma unroll
        for (int r = 0; r < 4; ++r)
          racc[r][ci] = __builtin_amdgcn_mfma_f32_16x16x32_bf16(A[r], W2[ci][ks], racc[r][ci], 0, 0, 0);
    }

    // raw barrier: LDS drained, glds prefetch stays in flight (NO vmcnt here)
    asm volatile("s_waitcnt lgkmcnt(0)" ::: "memory");
    __builtin_amdgcn_s_barrier();
    __builtin_amdgcn_sched_barrier(0);

    // ---- Phase D: racc = relu(racc) * ex[row][2w+ci]
    #pragma unroll
    for (int r = 0; r < 4; ++r)
      #pragma unroll
      for (int j = 0; j < 4; ++j) {
        const int row = 16 * r + 4 * lg + j;
        const float2 e = *(const float2*)(exs + row * 16 + 2 * w);
        float v0 = racc[r][0][j]; v0 = v0 > 0.f ? v0 : 0.f; racc[r][0][j] = v0 * e.x;
        float v1 = racc[r][1][j]; v1 = v1 > 0.f ? v1 : 0.f; racc[r][1][j] = v1 * e.y;
      }

    // ---- Phase E: in-register segmented column sums; interior -> store, edge -> atomic
    unsigned long long mm = bmask;
    while (mm) {
      int a = __builtin_ctzll(mm);
      mm &= mm - 1;
      int b = mm ? __builtin_ctzll(mm) : 64;
      int g = __shfl(gv, a, 64);
      float s0 = 0.f, s1 = 0.f;
      #pragma unroll
      for (int r = 0; r < 4; ++r)
        #pragma unroll
        for (int j = 0; j < 4; ++j) {
          const int row = 16 * r + 4 * lg + j;
          const float msk = ((unsigned)(row - a) < (unsigned)(b - a)) ? 1.f : 0.f;
          s0 = fmaf(msk, racc[r][0][j], s0);
          s1 = fmaf(msk, racc[r][1][j], s1);
        }
      s0 += __shfl_xor(s0, 16, 64); s0 += __shfl_xor(s0, 32, 64);
      s1 += __shfl_xor(s1, 16, 64); s1 += __shfl_xor(s1, 32, 64);
      const bool edge = (a == 0) || (b == 64);
      if (lane < 16) {
        float* dst = out + (size_t)g * GDIM + 32 * w + lane;
        if (edge) { atomicAdd(dst, s0); atomicAdd(dst + 16, s1); }
        else      { dst[0] = s0; dst[16] = s1; }
      }
    }
  }
}

// ---------------- epilogue: out[g][c] /= denom[g][c/16]; empty graphs -> 0 ----------------
__global__ void k_div(float* __restrict__ out, const float* __restrict__ denom) {
  int i = blockIdx.x * 256 + threadIdx.x;
  if (i >= NG * GDIM / 4) return;
  float d = denom[(size_t)(i >> 6) * NH + ((i & 63) >> 2)];
  float r = d > 0.f ? 1.0f / d : 0.f;
  float4 v = ((float4*)out)[i];
  v.x *= r; v.y *= r; v.z *= r; v.w *= r;
  ((float4*)out)[i] = v;
}

extern "C" void kernel_launch(void* const* d_in, const int* in_sizes, int n_in,
                              void* d_out, int out_size, void* d_ws, size_t ws_size,
                              hipStream_t stream) {
  (void)in_sizes; (void)n_in; (void)out_size; (void)ws_size;
  const float* X  = (const float*)d_in[0];
  const int* seg  = (const int*)d_in[1];
  const float* s1 = (const float*)d_in[3];
  const float* s2 = (const float*)d_in[4];
  const float* t1 = (const float*)d_in[5];
  const float* t2 = (const float*)d_in[6];
  float* out = (float*)d_out;
  char* ws = (char*)d_ws;

  unsigned short* WB = (unsigned short*)ws;
  float* denom = (float*)(ws + (1 << 19));

  k_prep<<<392, 256, 0, stream>>>(s1, s2, t1, t2, WB);
  k_zero<<<13282, 256, 0, stream>>>(out, denom);
  k_main<<<NTILES / TPB, 512, 0, stream>>>(X, WB, WB + 32768, WB + 98304, WB + 65536,
                                           seg, denom, out);
  k_div<<<12500, 256, 0, stream>>>(out, denom);
}